// Round 5
// baseline (699.967 us; speedup 1.0000x reference)
//
#include <hip/hip_runtime.h>

// 3-layer GraphConv (PyG) + softmax, 100k nodes, 1.6M edges, f32 in/out.
// R2: f32 global atomics ~306G/s scattered -> pull-gather wins.
// R9: fully deterministic build (zero global atomics). gather32 = 44.5us.
// R10: staged gather unroll: NULL -> not latency-bound.
// R11: fp16 t FAILED accuracy (5.08e-2). R12: int16 row-scaled PASSES.
// R13: int16 gathers (half bytes): NULL -> not bytes-bound.
// R14: scale-in-line (half line-reqs): -5us only -> not request-bound.
//      Three nulls => gather INNER LOOP is not the cost. Remaining
//      structure: place_merge's 2nd sort pass (12.8MB + per-edge LDS
//      atomics x2), per-node degree divergence (Poisson-16 in 4-node
//      waves ~40% idle), rowptr/srcs index streams.
// R15: gather by BUCKET directly from records: drop place_merge/rowptr/
//      srcs_sorted; edge-parallel lanes (no divergence); padded-LDS f32
//      atomic accumulate; coalesced rootacc+acc writeback. 13->10 kernels.

#define RNODES 128
#define NB_MAX 1024
#define CH 4096            // edges per chunk
#define CMAX 512           // max chunks (scan_chunkhist: one chunk/thread)

// ------- split linear: y=0: t=quant(x@Wrel) int16 (+scale); y=1: acc=x@Wroot+b
// Fout==32: t stride 32 shorts (64B rows), scale in separate tscale[]
// Fout==16: t stride 32 shorts (64B rows): {q[16] | f32 scale @byte32 | pad}
// Fout==2 : t stride 4 shorts (8B rows): {q0,q1 | f32 scale}
template <int Fin, int Fout, bool RELU>
__global__ void linear_q2_kernel(const float* __restrict__ x,
                                 const float* __restrict__ Wrel,
                                 const float* __restrict__ Wroot,
                                 const float* __restrict__ bias,
                                 short* __restrict__ t,
                                 float* __restrict__ tscale,
                                 float* __restrict__ acc, int N) {
    const bool rootTask = (blockIdx.y != 0);
    const float* __restrict__ W = rootTask ? Wroot : Wrel;

    int n = blockIdx.x * blockDim.x + threadIdx.x;
    if (n >= N) return;

    float o[Fout];
#pragma unroll
    for (int f = 0; f < Fout; ++f) o[f] = 0.f;

    const float* xr = x + (size_t)n * Fin;
#pragma unroll
    for (int k = 0; k < Fin; k += 4) {
        float4 v = *(const float4*)(xr + k);
        if (RELU) {
            v.x = fmaxf(v.x, 0.f); v.y = fmaxf(v.y, 0.f);
            v.z = fmaxf(v.z, 0.f); v.w = fmaxf(v.w, 0.f);
        }
        const float xv[4] = {v.x, v.y, v.z, v.w};
#pragma unroll
        for (int kk = 0; kk < 4; ++kk) {
            const float* wr = W + (size_t)(k + kk) * Fout;
#pragma unroll
            for (int f = 0; f < Fout; ++f)
                o[f] = fmaf(xv[kk], wr[f], o[f]);
        }
    }

    if (rootTask) {
#pragma unroll
        for (int f = 0; f < Fout; ++f) o[f] += bias[f];
        float* arow = acc + (size_t)n * Fout;
        if constexpr (Fout >= 4) {
#pragma unroll
            for (int f = 0; f < Fout; f += 4)
                *(float4*)(arow + f) = make_float4(o[f], o[f+1], o[f+2], o[f+3]);
        } else {
            *(float2*)arow = make_float2(o[0], o[1]);
        }
    } else {
        float m = 0.f;
#pragma unroll
        for (int f = 0; f < Fout; ++f) m = fmaxf(m, fabsf(o[f]));
        const float inv = (m > 0.f) ? (32767.0f / m) : 0.f;
        const float sc  = m * (1.0f / 32767.0f);

        short q[Fout];
#pragma unroll
        for (int f = 0; f < Fout; ++f) q[f] = (short)__float2int_rn(o[f] * inv);

        if constexpr (Fout == 32) {
            tscale[n] = sc;
            short* trow = t + (size_t)n * 32;
#pragma unroll
            for (int f = 0; f < 32; f += 8)
                *(int4*)(trow + f) = *(const int4*)(q + f);    // 16B stores
        } else if constexpr (Fout == 16) {
            short* trow = t + (size_t)n * 32;                  // stride 64B
            *(int4*)(trow)     = *(const int4*)(q);
            *(int4*)(trow + 8) = *(const int4*)(q + 8);
            ((float*)trow)[8]  = sc;                           // byte offset 32
        } else {
            int2 r;
            r.x = (int)(unsigned short)q[0] | ((int)q[1] << 16);
            r.y = __float_as_int(sc);
            *(int2*)(t + (size_t)n * 4) = r;
        }
    }
}

// ---------------- legacy f32 linear (fallback path only) -------------------
template <int Fin, int Fout, bool RELU>
__global__ void linear2_kernel(const float* __restrict__ x,
                               const float* __restrict__ Wrel,
                               const float* __restrict__ Wroot,
                               const float* __restrict__ bias,
                               float* __restrict__ t,
                               float* __restrict__ acc, int N) {
    const bool rootTask = (blockIdx.y != 0);
    const float* __restrict__ W = rootTask ? Wroot : Wrel;
    float* __restrict__ outp    = rootTask ? acc : t;

    int n = blockIdx.x * blockDim.x + threadIdx.x;
    if (n >= N) return;

    float o[Fout];
#pragma unroll
    for (int f = 0; f < Fout; ++f) o[f] = 0.f;

    const float* xr = x + (size_t)n * Fin;
#pragma unroll
    for (int k = 0; k < Fin; k += 4) {
        float4 v = *(const float4*)(xr + k);
        if (RELU) {
            v.x = fmaxf(v.x, 0.f); v.y = fmaxf(v.y, 0.f);
            v.z = fmaxf(v.z, 0.f); v.w = fmaxf(v.w, 0.f);
        }
        const float xv[4] = {v.x, v.y, v.z, v.w};
#pragma unroll
        for (int kk = 0; kk < 4; ++kk) {
            const float* wr = W + (size_t)(k + kk) * Fout;
#pragma unroll
            for (int f = 0; f < Fout; ++f)
                o[f] = fmaf(xv[kk], wr[f], o[f]);
        }
    }
    if (rootTask) {
#pragma unroll
        for (int f = 0; f < Fout; ++f) o[f] += bias[f];
    }
    float* op = outp + (size_t)n * Fout;
    if constexpr (Fout >= 4) {
#pragma unroll
        for (int f = 0; f < Fout; f += 4)
            *(float4*)(op + f) = make_float4(o[f], o[f + 1], o[f + 2], o[f + 3]);
    } else {
        *(float2*)op = make_float2(o[0], o[1]);
    }
}

// ---------------- build step 1: per-chunk LDS histogram --------------------
__global__ void hist_chunked_kernel(const int* __restrict__ dst,
                                    int* __restrict__ chunkhist,
                                    int nE, int NB) {
    __shared__ int h[NB_MAX];
    const int c  = blockIdx.x;
    const int e0 = c * CH, e1 = min(e0 + CH, nE);
    for (int b = threadIdx.x; b < NB; b += blockDim.x) h[b] = 0;
    __syncthreads();
    for (int e = e0 + threadIdx.x; e < e1; e += blockDim.x)
        atomicAdd(&h[dst[e] >> 7], 1);
    __syncthreads();
    for (int b = threadIdx.x; b < NB; b += blockDim.x)
        chunkhist[(size_t)c * NB + b] = h[b];          // contiguous row flush
}

// ---------------- build step 2: column scan (per bucket over chunks) -------
__global__ void scan_chunkhist_kernel(int* __restrict__ chunkhist,
                                      int* __restrict__ gtotal,
                                      int C, int NB) {
    __shared__ int s[CMAX];
    const int b = blockIdx.x;
    const int t = threadIdx.x;
    int v = (t < C) ? chunkhist[(size_t)t * NB + b] : 0;
    s[t] = v;
    __syncthreads();
    for (int off = 1; off < CMAX; off <<= 1) {
        int u = (t >= off) ? s[t - off] : 0;
        __syncthreads();
        s[t] += u;
        __syncthreads();
    }
    if (t < C) chunkhist[(size_t)t * NB + b] = s[t] - v;   // exclusive
    if (t == CMAX - 1) gtotal[b] = s[t];                   // inclusive total
}

// ---------------- build step 3: bucket scan (single block) -----------------
__global__ void scan_buckets_kernel(const int* __restrict__ gtotal,
                                    int* __restrict__ bptr, int NB, int nE) {
    __shared__ int s[NB_MAX];
    int t = threadIdx.x;
    int own = (t < NB) ? gtotal[t] : 0;
    s[t] = own;
    __syncthreads();
    for (int off = 1; off < NB_MAX; off <<= 1) {
        int v = (t >= off) ? s[t - off] : 0;
        __syncthreads();
        s[t] += v;
        __syncthreads();
    }
    if (t < NB) bptr[t] = s[t] - own;
    if (t == 0) bptr[NB] = nE;
}

// ---------------- build step 4: deterministic placement --------------------
__global__ void bucketize_det_kernel(const int* __restrict__ src,
                                     const int* __restrict__ dst,
                                     const int* __restrict__ chunkpre,
                                     const int* __restrict__ bptr,
                                     unsigned int* __restrict__ records,
                                     int nE, int NB) {
    __shared__ int lcur[NB_MAX];
    const int c  = blockIdx.x;
    const int e0 = c * CH, e1 = min(e0 + CH, nE);
    for (int b = threadIdx.x; b < NB; b += blockDim.x)
        lcur[b] = bptr[b] + chunkpre[(size_t)c * NB + b];
    __syncthreads();
    for (int e = e0 + threadIdx.x; e < e1; e += blockDim.x) {
        int d = dst[e];
        int b = d >> 7;
        int pos = atomicAdd(&lcur[b], 1);                  // LDS-only atomic
        records[pos] = (unsigned int)src[e] | ((unsigned int)(d & 127) << 17);
    }
}

// ------- bucket gather: block b aggregates edges [bptr[b], bptr[b+1]) ------
// Edge-parallel: F/2 lanes per edge (F>=4) -> zero degree divergence.
// LDS acc padded to F+1 words/row so bank = (d*(F+1)+2fp)%32 varies with d.
// F==32: scale from tscale[]; F==16/2: scale inline in the row.
template <int F, bool SOFTMAX>
__global__ void bucket_gather_kernel(const short* __restrict__ t,
                                     const float* __restrict__ tscale,
                                     const unsigned int* __restrict__ records,
                                     const int* __restrict__ bptr,
                                     const float* __restrict__ rootacc,
                                     float* __restrict__ out, int N) {
    __shared__ float accs[RNODES * (F + 1)];
    const int b    = blockIdx.x;
    const int base = b * RNODES;
    const int nn   = min(RNODES, N - base);
    const int beg  = bptr[b], end = bptr[b + 1];
    const int tid  = threadIdx.x;

    for (int i = tid; i < RNODES * (F + 1); i += blockDim.x) accs[i] = 0.f;
    __syncthreads();

    if constexpr (F >= 4) {
        constexpr int LPE = F / 2;                  // lanes per edge
        const int epi = blockDim.x / LPE;           // edges per iteration
        const int le  = tid / LPE;
        const int fp  = tid % LPE;
        for (int e = beg + le; e < end; e += epi) {
            unsigned int rec = records[e];          // broadcast within group
            int s = (int)(rec & 0x1FFFFu);
            int d = (int)(rec >> 17);
            float lo, hi, sc;
            if constexpr (F == 32) {
                int qv = ((const int*)t)[(size_t)s * 16 + fp];   // 64B line
                sc = tscale[s];                                   // broadcast
                lo = (float)((short)(qv & 0xFFFF));
                hi = (float)(qv >> 16);
            } else {                                // F == 16, inline scale
                const int* row = (const int*)t + (size_t)s * 16;
                int qv = row[fp];
                sc = __int_as_float(row[8]);        // same 64B line
                lo = (float)((short)(qv & 0xFFFF));
                hi = (float)(qv >> 16);
            }
            float* ar = accs + d * (F + 1) + 2 * fp;
            atomicAdd(ar,     sc * lo);
            atomicAdd(ar + 1, sc * hi);
        }
    } else {                                        // F == 2: 1 lane per edge
        for (int e = beg + tid; e < end; e += blockDim.x) {
            unsigned int rec = records[e];
            int s = (int)(rec & 0x1FFFFu);
            int d = (int)(rec >> 17);
            int2 r = ((const int2*)t)[s];           // 8B row {q0q1, scale}
            float sc = __int_as_float(r.y);
            float* ar = accs + d * 3;
            atomicAdd(ar,     sc * (float)((short)(r.x & 0xFFFF)));
            atomicAdd(ar + 1, sc * (float)(r.x >> 16));
        }
    }
    __syncthreads();

    if constexpr (!SOFTMAX) {
        // coalesced writeback: out = rootacc + acc
        for (int i = tid; i < nn * F; i += blockDim.x) {
            int node = i / F, f = i % F;            // F pow2: compiler folds
            float v = rootacc[(size_t)(base + node) * F + f]
                    + accs[node * (F + 1) + f];
            out[(size_t)(base + node) * F + f] = v;
        }
    } else {
        for (int node = tid; node < nn; node += blockDim.x) {
            const float2 r0 = *(const float2*)(rootacc + (size_t)(base + node) * 2);
            float a = r0.x + accs[node * 3];
            float bb = r0.y + accs[node * 3 + 1];
            float m = fmaxf(a, bb);
            float ea = __expf(a - m), eb = __expf(bb - m);
            float inv = 1.0f / (ea + eb);
            *(float2*)(out + (size_t)(base + node) * 2) = make_float2(ea * inv, eb * inv);
        }
    }
}

// ---------------- fallback (R2 atomic path) --------------------------------
template <int F>
__global__ void scatter_kernel(const float* __restrict__ t,
                               const int* __restrict__ src,
                               const int* __restrict__ dst,
                               float* __restrict__ acc, int nE) {
    int tid = blockIdx.x * blockDim.x + threadIdx.x;
    int e = tid / F;
    if (e >= nE) return;
    int f = tid & (F - 1);
    atomicAdd(acc + (long)dst[e] * F + f, t[(long)src[e] * F + f]);
}

__global__ void softmax2_kernel(const float* __restrict__ h, float* __restrict__ out, int N) {
    int n = blockIdx.x * blockDim.x + threadIdx.x;
    if (n >= N) return;
    float a = h[2 * n], b = h[2 * n + 1];
    float m = fmaxf(a, b);
    float ea = __expf(a - m), eb = __expf(b - m);
    float inv = 1.0f / (ea + eb);
    out[2 * n] = ea * inv;
    out[2 * n + 1] = eb * inv;
}

extern "C" void kernel_launch(void* const* d_in, const int* in_sizes, int n_in,
                              void* d_out, int out_size, void* d_ws, size_t ws_size,
                              hipStream_t stream) {
    const float* z      = (const float*)d_in[0];
    const int*   ei     = (const int*)d_in[1];
    const float* Wrel1  = (const float*)d_in[2];
    const float* Wroot1 = (const float*)d_in[3];
    const float* b1     = (const float*)d_in[4];
    const float* Wrel2  = (const float*)d_in[5];
    const float* Wroot2 = (const float*)d_in[6];
    const float* b2     = (const float*)d_in[7];
    const float* Wrel3  = (const float*)d_in[8];
    const float* Wroot3 = (const float*)d_in[9];
    const float* b3     = (const float*)d_in[10];

    const int N  = in_sizes[0] / 64;   // 100000
    const int nE = in_sizes[1] / 2;    // 1600000
    const int* src = ei;
    const int* dst = ei + nE;
    const int NB = (N + RNODES - 1) / RNODES;   // 782
    const int C  = (nE + CH - 1) / CH;          // 391 chunks

    // ---- flat workspace layout (no aliasing) ----
    char* wsb = (char*)d_ws;
    size_t off = 0;
    auto take = [&](size_t bytes) -> void* {
        void* p = (void*)(wsb + off);
        off = (off + bytes + 255) & ~(size_t)255;
        return p;
    };
    int*          chunkhist   = (int*)take((size_t)CMAX * NB_MAX * 4);
    int*          gtotal      = (int*)take((size_t)NB_MAX * 4);
    int*          bptr        = (int*)take((size_t)(NB_MAX + 1) * 4);
    unsigned int* records     = (unsigned int*)take((size_t)nE * 4);
    short*        t1          = (short*)take((size_t)N * 32 * 2);   // 64B rows
    float*        s1          = (float*)take((size_t)N * 4);        // L1 scale
    float*        h1          = (float*)take((size_t)N * 32 * 4);
    short*        t2          = (short*)take((size_t)N * 64);       // 64B rows w/ scale
    float*        h2          = (float*)take((size_t)N * 16 * 4);
    short*        t3          = (short*)take((size_t)N * 8);        // 8B rows w/ scale
    float*        h3          = (float*)take((size_t)N * 2 * 4);
    const size_t needed = off;

    const int B = 256;
    const int nodeBlocks = (N + B - 1) / B;
    const dim3 linGrid(nodeBlocks, 2);       // y=0: rel(quant)->t, y=1: root+b->acc
    const bool packOK = (N <= (1 << 17)) && (NB <= NB_MAX) && (C <= CMAX);

    if (ws_size >= needed && packOK) {
        // ---- build: zero-global-atomic bucket grouping (4 kernels) ----
        hist_chunked_kernel<<<C, 512, 0, stream>>>(dst, chunkhist, nE, NB);
        scan_chunkhist_kernel<<<NB, CMAX, 0, stream>>>(chunkhist, gtotal, C, NB);
        scan_buckets_kernel<<<1, NB_MAX, 0, stream>>>(gtotal, bptr, NB, nE);
        bucketize_det_kernel<<<C, 512, 0, stream>>>(src, dst, chunkhist, bptr, records, nE, NB);

        // ---- Layer 1: 64 -> 32 ----
        linear_q2_kernel<64, 32, false><<<linGrid, B, 0, stream>>>(
            z, Wrel1, Wroot1, b1, t1, s1, h1, N);
        bucket_gather_kernel<32, false><<<NB, 512, 0, stream>>>(
            t1, s1, records, bptr, h1, h1, N);

        // ---- Layer 2: 32 -> 16 ----
        linear_q2_kernel<32, 16, true><<<linGrid, B, 0, stream>>>(
            h1, Wrel2, Wroot2, b2, t2, nullptr, h2, N);
        bucket_gather_kernel<16, false><<<NB, 512, 0, stream>>>(
            t2, nullptr, records, bptr, h2, h2, N);

        // ---- Layer 3: 16 -> 2, softmax fused ----
        linear_q2_kernel<16, 2, true><<<linGrid, B, 0, stream>>>(
            h2, Wrel3, Wroot3, b3, t3, nullptr, h3, N);
        bucket_gather_kernel<2, true><<<NB, 512, 0, stream>>>(
            t3, nullptr, records, bptr, h3, (float*)d_out, N);
    } else {
        // ---- fallback: R2 atomic-scatter path (all f32, ping-pong layout) ----
        float* regionA = (float*)d_ws;
        float* regionB = regionA + (size_t)N * 32;
        float* ft1 = regionA;
        float* fh1 = regionB;
        float* ft2 = regionA;
        float* fh2 = regionA + (size_t)N * 16;
        float* ft3 = regionB;
        float* fh3 = regionB + (size_t)N * 2;
        linear2_kernel<64, 32, false><<<linGrid, B, 0, stream>>>(z, Wrel1, Wroot1, b1, ft1, fh1, N);
        scatter_kernel<32><<<((size_t)nE * 32 + B - 1) / B, B, 0, stream>>>(ft1, src, dst, fh1, nE);
        linear2_kernel<32, 16, true><<<linGrid, B, 0, stream>>>(fh1, Wrel2, Wroot2, b2, ft2, fh2, N);
        scatter_kernel<16><<<((size_t)nE * 16 + B - 1) / B, B, 0, stream>>>(ft2, src, dst, fh2, nE);
        linear2_kernel<16, 2, true><<<linGrid, B, 0, stream>>>(fh2, Wrel3, Wroot3, b3, ft3, fh3, N);
        scatter_kernel<2><<<((size_t)nE * 2 + B - 1) / B, B, 0, stream>>>(ft3, src, dst, fh3, nE);
        softmax2_kernel<<<nodeBlocks, B, 0, stream>>>(fh3, (float*)d_out, N);
    }
}

// Round 6
// 255.700 us; speedup vs baseline: 2.7375x; 2.7375x over previous
//
#include <hip/hip_runtime.h>

// 3-layer GraphConv (PyG) + softmax, 100k nodes, 1.6M edges, f32 in/out.
// R2: f32 global atomics ~306G/s scattered -> pull-gather wins.
// R9: fully deterministic build (zero global atomics). gather32 = 44.5us.
// R10: staged gather unroll: NULL -> not latency-bound.
// R11: fp16 t FAILED accuracy (5.08e-2). R12: int16 row-scaled PASSES.
// R13: int16 gathers (half bytes): NULL -> not bytes-bound.
// R14: scale-in-line (half line-reqs): -5us -> not request-bound. 243us.
// R15: bucket_gather w/ LDS atomics: DISASTER (343us/dispatch, LDS-atomic
//      serialization + 64MB HBM refetch). Reverted to R14 structure.
// R16: launch-graph compression, kernels unchanged:
//      K1 {hist || lin1-rel}, K2 {scan_chunkhist || lin1-root} (independent
//      work shares a launch via blockIdx.y); scan_buckets ELIMINATED
//      (bucketize/place_merge recompute the 1024-entry bucket prefix
//      locally in LDS from gtotal). 11 -> 9 launches, build hidden under
//      linears. Gather/linear inner loops identical to R14.

#define RNODES 128
#define NB_MAX 1024
#define CH 4096            // edges per chunk
#define CMAX 512           // max chunks (scan_chunkhist: one chunk/thread)

// ================= device bodies for the quantizing linear =================
template <int Fin, int Fout, bool RELU>
__device__ __forceinline__ void lin_compute(const float* __restrict__ x,
                                            const float* __restrict__ W,
                                            int n, float* o) {
#pragma unroll
    for (int f = 0; f < Fout; ++f) o[f] = 0.f;
    const float* xr = x + (size_t)n * Fin;
#pragma unroll
    for (int k = 0; k < Fin; k += 4) {
        float4 v = *(const float4*)(xr + k);
        if (RELU) {
            v.x = fmaxf(v.x, 0.f); v.y = fmaxf(v.y, 0.f);
            v.z = fmaxf(v.z, 0.f); v.w = fmaxf(v.w, 0.f);
        }
        const float xv[4] = {v.x, v.y, v.z, v.w};
#pragma unroll
        for (int kk = 0; kk < 4; ++kk) {
            const float* wr = W + (size_t)(k + kk) * Fout;
#pragma unroll
            for (int f = 0; f < Fout; ++f)
                o[f] = fmaf(xv[kk], wr[f], o[f]);
        }
    }
}

// Fout==32: 64B data row, scale in separate tscale[] (gather32 control form)
// Fout==16: 64B row {q[16] | f32 scale @byte32 | pad}
// Fout==2 : 8B row {q0,q1 | f32 scale}
template <int Fout>
__device__ __forceinline__ void store_quant(short* __restrict__ t,
                                            float* __restrict__ tscale,
                                            int n, const float* o) {
    float m = 0.f;
#pragma unroll
    for (int f = 0; f < Fout; ++f) m = fmaxf(m, fabsf(o[f]));
    const float inv = (m > 0.f) ? (32767.0f / m) : 0.f;
    const float sc  = m * (1.0f / 32767.0f);
    short q[Fout];
#pragma unroll
    for (int f = 0; f < Fout; ++f) q[f] = (short)__float2int_rn(o[f] * inv);

    if constexpr (Fout == 32) {
        tscale[n] = sc;
        short* trow = t + (size_t)n * 32;
#pragma unroll
        for (int f = 0; f < 32; f += 8)
            *(int4*)(trow + f) = *(const int4*)(q + f);        // 16B stores
    } else if constexpr (Fout == 16) {
        short* trow = t + (size_t)n * 32;                      // stride 64B
        *(int4*)(trow)     = *(const int4*)(q);
        *(int4*)(trow + 8) = *(const int4*)(q + 8);
        ((float*)trow)[8]  = sc;                               // byte offset 32
    } else {
        int2 r;
        r.x = (int)(unsigned short)q[0] | ((int)q[1] << 16);
        r.y = __float_as_int(sc);
        *(int2*)(t + (size_t)n * 4) = r;
    }
}

template <int Fout>
__device__ __forceinline__ void store_root(float* __restrict__ acc,
                                           const float* __restrict__ bias,
                                           int n, float* o) {
#pragma unroll
    for (int f = 0; f < Fout; ++f) o[f] += bias[f];
    float* arow = acc + (size_t)n * Fout;
    if constexpr (Fout >= 4) {
#pragma unroll
        for (int f = 0; f < Fout; f += 4)
            *(float4*)(arow + f) = make_float4(o[f], o[f+1], o[f+2], o[f+3]);
    } else {
        *(float2*)arow = make_float2(o[0], o[1]);
    }
}

// ------- standalone split linear (layers 2,3): y=0 rel(quant), y=1 root ----
template <int Fin, int Fout, bool RELU>
__global__ void linear_q2_kernel(const float* __restrict__ x,
                                 const float* __restrict__ Wrel,
                                 const float* __restrict__ Wroot,
                                 const float* __restrict__ bias,
                                 short* __restrict__ t,
                                 float* __restrict__ tscale,
                                 float* __restrict__ acc, int N) {
    int n = blockIdx.x * blockDim.x + threadIdx.x;
    if (n >= N) return;
    float o[Fout];
    if (blockIdx.y != 0) {
        lin_compute<Fin, Fout, RELU>(x, Wroot, n, o);
        store_root<Fout>(acc, bias, n, o);
    } else {
        lin_compute<Fin, Fout, RELU>(x, Wrel, n, o);
        store_quant<Fout>(t, tscale, n, o);
    }
}

// ================= K1: hist_chunked || linear1-rel =========================
__global__ void k1_hist_lin1rel_kernel(const int* __restrict__ dst,
                                       int* __restrict__ chunkhist,
                                       int nE, int NB,
                                       const float* __restrict__ z,
                                       const float* __restrict__ Wrel1,
                                       short* __restrict__ t1,
                                       float* __restrict__ s1, int N) {
    if (blockIdx.y == 0) {
        __shared__ int h[NB_MAX];
        const int c  = blockIdx.x;
        const int e0 = c * CH, e1 = min(e0 + CH, nE);
        for (int b = threadIdx.x; b < NB; b += blockDim.x) h[b] = 0;
        __syncthreads();
        for (int e = e0 + threadIdx.x; e < e1; e += blockDim.x)
            atomicAdd(&h[dst[e] >> 7], 1);
        __syncthreads();
        for (int b = threadIdx.x; b < NB; b += blockDim.x)
            chunkhist[(size_t)c * NB + b] = h[b];      // contiguous row flush
    } else {
        int n = blockIdx.x * blockDim.x + threadIdx.x;
        if (n >= N) return;
        float o[32];
        lin_compute<64, 32, false>(z, Wrel1, n, o);
        store_quant<32>(t1, s1, n, o);
    }
}

// ================= K2: scan_chunkhist || linear1-root ======================
__global__ void k2_scan_lin1root_kernel(int* __restrict__ chunkhist,
                                        int* __restrict__ gtotal,
                                        int C, int NB,
                                        const float* __restrict__ z,
                                        const float* __restrict__ Wroot1,
                                        const float* __restrict__ b1,
                                        float* __restrict__ h1, int N) {
    if (blockIdx.y == 0) {
        __shared__ int s[CMAX];
        const int b = blockIdx.x;                      // bucket, < NB
        const int t = threadIdx.x;                     // blockDim == CMAX
        int v = (t < C) ? chunkhist[(size_t)t * NB + b] : 0;
        s[t] = v;
        __syncthreads();
        for (int off = 1; off < CMAX; off <<= 1) {
            int u = (t >= off) ? s[t - off] : 0;
            __syncthreads();
            s[t] += u;
            __syncthreads();
        }
        if (t < C) chunkhist[(size_t)t * NB + b] = s[t] - v;   // exclusive
        if (t == CMAX - 1) gtotal[b] = s[t];                   // inclusive total
    } else {
        int n = blockIdx.x * blockDim.x + threadIdx.x;
        if (n >= N) return;
        float o[32];
        lin_compute<64, 32, false>(z, Wroot1, n, o);
        store_root<32>(h1, b1, n, o);
    }
}

// ====== K3: bucketize with LOCAL bucket-prefix scan (no scan_buckets) ======
// 1024 threads. Each block scans gtotal[0..NB) in LDS (kernel boundary after
// K2 guarantees gtotal complete), then places its chunk's edges.
__global__ void k3_bucketize_kernel(const int* __restrict__ src,
                                    const int* __restrict__ dst,
                                    const int* __restrict__ chunkpre,
                                    const int* __restrict__ gtotal,
                                    unsigned int* __restrict__ records,
                                    int nE, int NB) {
    __shared__ int s[NB_MAX];
    __shared__ int lcur[NB_MAX];
    const int t = threadIdx.x;
    int own = (t < NB) ? gtotal[t] : 0;
    s[t] = own;
    __syncthreads();
    for (int off = 1; off < NB_MAX; off <<= 1) {
        int v = (t >= off) ? s[t - off] : 0;
        __syncthreads();
        s[t] += v;
        __syncthreads();
    }
    // exclusive prefix at b = s[b] - gtotal[b]
    const int c = blockIdx.x;
    for (int b = t; b < NB; b += blockDim.x)
        lcur[b] = (s[b] - gtotal[b]) + chunkpre[(size_t)c * NB + b];
    __syncthreads();
    const int e0 = c * CH, e1 = min(e0 + CH, nE);
    for (int e = e0 + t; e < e1; e += blockDim.x) {
        int d = dst[e];
        int b = d >> 7;
        int pos = atomicAdd(&lcur[b], 1);              // LDS-only atomic
        records[pos] = (unsigned int)src[e] | ((unsigned int)(d & 127) << 17);
    }
}

// ====== K4: place_merge with LOCAL beg-reduction (no bptr array) ===========
// 1024 threads. beg = sum(gtotal[0..b)) via LDS tree reduce (b < 1024).
__global__ void k4_place_merge_kernel(const unsigned int* __restrict__ records,
                                      const int* __restrict__ gtotal,
                                      int* __restrict__ rowptr,
                                      int* __restrict__ srcs_sorted,
                                      int N, int nE, int NB) {
    __shared__ int red[NB_MAX];
    __shared__ int hist[RNODES];
    __shared__ int s[RNODES];
    __shared__ int lcur[RNODES];
    const int b = blockIdx.x;
    const int t = threadIdx.x;

    red[t] = (t < b) ? gtotal[t] : 0;                  // b < 1024: <=1 term
    __syncthreads();
    for (int off = NB_MAX / 2; off > 0; off >>= 1) {
        if (t < off) red[t] += red[t + off];
        __syncthreads();
    }
    const int beg = red[0];
    const int end = beg + gtotal[b];

    const int base = b * RNODES;
    const int nn   = min(RNODES, N - base);

    if (t < RNODES) hist[t] = 0;
    __syncthreads();
    for (int i = beg + t; i < end; i += blockDim.x)
        atomicAdd(&hist[records[i] >> 17], 1);
    __syncthreads();

    if (t < RNODES) s[t] = hist[t];
    __syncthreads();
    for (int off = 1; off < RNODES; off <<= 1) {
        int v = (t < RNODES && t >= off) ? s[t - off] : 0;
        __syncthreads();
        if (t < RNODES && t >= off) s[t] += v;
        __syncthreads();
    }
    if (t < nn) {
        int ex = beg + s[t] - hist[t];
        rowptr[base + t] = ex;
        lcur[t] = ex;
    }
    if (b == NB - 1 && t == 0) rowptr[N] = nE;
    __syncthreads();

    for (int i = beg + t; i < end; i += blockDim.x) {
        unsigned int rec = records[i];
        int pos = atomicAdd(&lcur[rec >> 17], 1);
        srcs_sorted[pos] = (int)(rec & 0x1FFFFu);
    }
}

// ------- L1 gather (R14, proven): int16 rows + separate scale --------------
// F=32: 16 lanes/node, each owns one short2 (2 features).
template <int F, bool SOFTMAX>
__global__ void gather_agg_q_kernel(const short* __restrict__ t,
                                    const float* __restrict__ tscale,
                                    const int* __restrict__ rowptr,
                                    const int* __restrict__ srcs,
                                    const float* __restrict__ rootacc,
                                    float* __restrict__ out, int N) {
    constexpr int P = (F >= 4) ? (F / 2) : 1;   // lanes per node
    constexpr int S = F / 2;                    // row stride in short2 (ints)
    int tid = blockIdx.x * blockDim.x + threadIdx.x;
    int n  = (P == 1) ? tid : (tid / P);
    int fp = (P == 1) ? 0   : (tid & (P - 1));
    if (n >= N) return;

    const int* tp = (const int*)t;              // short2 viewed as int
    int beg = rowptr[n], end = rowptr[n + 1];
    float sx = 0.f, sy = 0.f;
    int e = beg;
    for (; e + 8 <= end; e += 8) {
        int s[8];
#pragma unroll
        for (int u = 0; u < 8; ++u) s[u] = srcs[e + u];
        int q[8]; float sc[8];
#pragma unroll
        for (int u = 0; u < 8; ++u) {
            q[u]  = tp[s[u] * S + fp];
            sc[u] = tscale[s[u]];
        }
#pragma unroll
        for (int u = 0; u < 8; ++u) {
            float lo = (float)((short)(q[u] & 0xFFFF));
            float hi = (float)(q[u] >> 16);
            sx = fmaf(sc[u], lo, sx);
            sy = fmaf(sc[u], hi, sy);
        }
    }
    for (; e < end; ++e) {
        int s0 = srcs[e];
        int qv = tp[s0 * S + fp];
        float sc = tscale[s0];
        sx = fmaf(sc, (float)((short)(qv & 0xFFFF)), sx);
        sy = fmaf(sc, (float)(qv >> 16), sy);
    }

    const float2 r0 = *(const float2*)(rootacc + (size_t)n * F + 2 * fp);
    float a = r0.x + sx, b = r0.y + sy;
    if (!SOFTMAX) {
        *(float2*)(out + (size_t)n * F + 2 * fp) = make_float2(a, b);
    } else {
        float m = fmaxf(a, b);
        float ea = __expf(a - m), eb = __expf(b - m);
        float inv = 1.0f / (ea + eb);
        *(float2*)(out + (size_t)n * 2) = make_float2(ea * inv, eb * inv);
    }
}

// ------- L2 gather (R14): 64B rows {q[16] | scale | pad}, scale L1-hit -----
__global__ void gather16_inl_kernel(const short* __restrict__ t,
                                    const int* __restrict__ rowptr,
                                    const int* __restrict__ srcs,
                                    const float* __restrict__ rootacc,
                                    float* __restrict__ out, int N) {
    int tid = blockIdx.x * blockDim.x + threadIdx.x;
    int n  = tid >> 3;
    int fp = tid & 7;
    if (n >= N) return;

    const int* tp = (const int*)t;              // 16 ints per row (64B)
    int beg = rowptr[n], end = rowptr[n + 1];
    float sx = 0.f, sy = 0.f;
    int e = beg;
    for (; e + 8 <= end; e += 8) {
        int s[8];
#pragma unroll
        for (int u = 0; u < 8; ++u) s[u] = srcs[e + u];
        int q[8]; float sc[8];
#pragma unroll
        for (int u = 0; u < 8; ++u) {
            const int* row = tp + (size_t)s[u] * 16;
            q[u]  = row[fp];                           // line request
            sc[u] = __int_as_float(row[8]);            // same line: L1 hit
        }
#pragma unroll
        for (int u = 0; u < 8; ++u) {
            sx = fmaf(sc[u], (float)((short)(q[u] & 0xFFFF)), sx);
            sy = fmaf(sc[u], (float)(q[u] >> 16), sy);
        }
    }
    for (; e < end; ++e) {
        const int* row = tp + (size_t)srcs[e] * 16;
        int qv = row[fp];
        float sc = __int_as_float(row[8]);
        sx = fmaf(sc, (float)((short)(qv & 0xFFFF)), sx);
        sy = fmaf(sc, (float)(qv >> 16), sy);
    }

    const float2 r0 = *(const float2*)(rootacc + (size_t)n * 16 + 2 * fp);
    *(float2*)(out + (size_t)n * 16 + 2 * fp) = make_float2(r0.x + sx, r0.y + sy);
}

// ------- L3 gather (R14): 8B rows {q0,q1 | scale}, 4 lanes/node ------------
__global__ void gather2_inl_kernel(const short* __restrict__ t,
                                   const int* __restrict__ rowptr,
                                   const int* __restrict__ srcs,
                                   const float* __restrict__ rootacc,
                                   float* __restrict__ out, int N) {
    int tid = blockIdx.x * blockDim.x + threadIdx.x;
    int n  = tid >> 2;
    int fp = tid & 3;
    if (n >= N) return;

    const int2* tp = (const int2*)t;            // 8B rows
    int beg = rowptr[n], end = rowptr[n + 1];
    float sx = 0.f, sy = 0.f;
    int e = beg + fp;
    for (; e + 12 < end; e += 16) {
        int s0 = srcs[e], s1 = srcs[e + 4], s2 = srcs[e + 8], s3 = srcs[e + 12];
        int2 r0 = tp[s0], r1 = tp[s1], r2 = tp[s2], r3 = tp[s3];
        sx = fmaf(__int_as_float(r0.y), (float)((short)(r0.x & 0xFFFF)), sx);
        sy = fmaf(__int_as_float(r0.y), (float)(r0.x >> 16), sy);
        sx = fmaf(__int_as_float(r1.y), (float)((short)(r1.x & 0xFFFF)), sx);
        sy = fmaf(__int_as_float(r1.y), (float)(r1.x >> 16), sy);
        sx = fmaf(__int_as_float(r2.y), (float)((short)(r2.x & 0xFFFF)), sx);
        sy = fmaf(__int_as_float(r2.y), (float)(r2.x >> 16), sy);
        sx = fmaf(__int_as_float(r3.y), (float)((short)(r3.x & 0xFFFF)), sx);
        sy = fmaf(__int_as_float(r3.y), (float)(r3.x >> 16), sy);
    }
    for (; e < end; e += 4) {
        int2 r = tp[srcs[e]];
        sx = fmaf(__int_as_float(r.y), (float)((short)(r.x & 0xFFFF)), sx);
        sy = fmaf(__int_as_float(r.y), (float)(r.x >> 16), sy);
    }
    sx += __shfl_xor(sx, 1, 64); sy += __shfl_xor(sy, 1, 64);
    sx += __shfl_xor(sx, 2, 64); sy += __shfl_xor(sy, 2, 64);

    if (fp == 0) {
        const float2 r0 = *(const float2*)(rootacc + (size_t)n * 2);
        float a = r0.x + sx, b = r0.y + sy;
        float m = fmaxf(a, b);
        float ea = __expf(a - m), eb = __expf(b - m);
        float inv = 1.0f / (ea + eb);
        *(float2*)(out + (size_t)n * 2) = make_float2(ea * inv, eb * inv);
    }
}

// ---------------- fallback (R2 atomic path) --------------------------------
template <int Fin, int Fout, bool RELU>
__global__ void linear2_kernel(const float* __restrict__ x,
                               const float* __restrict__ Wrel,
                               const float* __restrict__ Wroot,
                               const float* __restrict__ bias,
                               float* __restrict__ t,
                               float* __restrict__ acc, int N) {
    const bool rootTask = (blockIdx.y != 0);
    const float* __restrict__ W = rootTask ? Wroot : Wrel;
    float* __restrict__ outp    = rootTask ? acc : t;

    int n = blockIdx.x * blockDim.x + threadIdx.x;
    if (n >= N) return;

    float o[Fout];
    lin_compute<Fin, Fout, RELU>(x, W, n, o);
    if (rootTask) {
#pragma unroll
        for (int f = 0; f < Fout; ++f) o[f] += bias[f];
    }
    float* op = outp + (size_t)n * Fout;
    if constexpr (Fout >= 4) {
#pragma unroll
        for (int f = 0; f < Fout; f += 4)
            *(float4*)(op + f) = make_float4(o[f], o[f + 1], o[f + 2], o[f + 3]);
    } else {
        *(float2*)op = make_float2(o[0], o[1]);
    }
}

template <int F>
__global__ void scatter_kernel(const float* __restrict__ t,
                               const int* __restrict__ src,
                               const int* __restrict__ dst,
                               float* __restrict__ acc, int nE) {
    int tid = blockIdx.x * blockDim.x + threadIdx.x;
    int e = tid / F;
    if (e >= nE) return;
    int f = tid & (F - 1);
    atomicAdd(acc + (long)dst[e] * F + f, t[(long)src[e] * F + f]);
}

__global__ void softmax2_kernel(const float* __restrict__ h, float* __restrict__ out, int N) {
    int n = blockIdx.x * blockDim.x + threadIdx.x;
    if (n >= N) return;
    float a = h[2 * n], b = h[2 * n + 1];
    float m = fmaxf(a, b);
    float ea = __expf(a - m), eb = __expf(b - m);
    float inv = 1.0f / (ea + eb);
    out[2 * n] = ea * inv;
    out[2 * n + 1] = eb * inv;
}

extern "C" void kernel_launch(void* const* d_in, const int* in_sizes, int n_in,
                              void* d_out, int out_size, void* d_ws, size_t ws_size,
                              hipStream_t stream) {
    const float* z      = (const float*)d_in[0];
    const int*   ei     = (const int*)d_in[1];
    const float* Wrel1  = (const float*)d_in[2];
    const float* Wroot1 = (const float*)d_in[3];
    const float* b1     = (const float*)d_in[4];
    const float* Wrel2  = (const float*)d_in[5];
    const float* Wroot2 = (const float*)d_in[6];
    const float* b2     = (const float*)d_in[7];
    const float* Wrel3  = (const float*)d_in[8];
    const float* Wroot3 = (const float*)d_in[9];
    const float* b3     = (const float*)d_in[10];

    const int N  = in_sizes[0] / 64;   // 100000
    const int nE = in_sizes[1] / 2;    // 1600000
    const int* src = ei;
    const int* dst = ei + nE;
    const int NB = (N + RNODES - 1) / RNODES;   // 782
    const int C  = (nE + CH - 1) / CH;          // 391 chunks

    // ---- flat workspace layout (no aliasing) ----
    char* wsb = (char*)d_ws;
    size_t off = 0;
    auto take = [&](size_t bytes) -> void* {
        void* p = (void*)(wsb + off);
        off = (off + bytes + 255) & ~(size_t)255;
        return p;
    };
    int*          chunkhist   = (int*)take((size_t)CMAX * NB_MAX * 4);
    int*          gtotal      = (int*)take((size_t)NB_MAX * 4);
    unsigned int* records     = (unsigned int*)take((size_t)nE * 4);
    int*          rowptr      = (int*)take((size_t)(N + 1) * 4);
    int*          srcs_sorted = (int*)take((size_t)nE * 4);
    short*        t1          = (short*)take((size_t)N * 32 * 2);   // 64B rows
    float*        s1          = (float*)take((size_t)N * 4);        // L1 scale
    float*        h1          = (float*)take((size_t)N * 32 * 4);
    short*        t2          = (short*)take((size_t)N * 64);       // 64B rows w/ scale
    float*        h2          = (float*)take((size_t)N * 16 * 4);
    short*        t3          = (short*)take((size_t)N * 8);        // 8B rows w/ scale
    float*        h3          = (float*)take((size_t)N * 2 * 4);
    const size_t needed = off;

    const int B = 256;
    const int nodeBlocks = (N + B - 1) / B;
    const dim3 linGrid(nodeBlocks, 2);
    const bool packOK = (N <= (1 << 17)) && (NB <= NB_MAX) && (C <= CMAX);

    if (ws_size >= needed && packOK) {
        // ---- K1: hist (391x512) || linear1-rel (196 of 391 x512) ----
        k1_hist_lin1rel_kernel<<<dim3(C, 2), 512, 0, stream>>>(
            dst, chunkhist, nE, NB, z, Wrel1, t1, s1, N);
        // ---- K2: scan_chunkhist (782x512) || linear1-root ----
        k2_scan_lin1root_kernel<<<dim3(NB, 2), CMAX, 0, stream>>>(
            chunkhist, gtotal, C, NB, z, Wroot1, b1, h1, N);
        // ---- K3: bucketize + local bucket scan (391x1024) ----
        k3_bucketize_kernel<<<C, NB_MAX, 0, stream>>>(
            src, dst, chunkhist, gtotal, records, nE, NB);
        // ---- K4: place_merge + local beg reduce (782x1024) ----
        k4_place_merge_kernel<<<NB, NB_MAX, 0, stream>>>(
            records, gtotal, rowptr, srcs_sorted, N, nE, NB);

        // ---- K5: gather layer 1 (64->32) ----
        gather_agg_q_kernel<32, false><<<((size_t)N * 16 + B - 1) / B, B, 0, stream>>>(
            t1, s1, rowptr, srcs_sorted, h1, h1, N);

        // ---- K6: linear layer 2 (32->16) ----
        linear_q2_kernel<32, 16, true><<<linGrid, B, 0, stream>>>(
            h1, Wrel2, Wroot2, b2, t2, nullptr, h2, N);
        // ---- K7: gather layer 2 ----
        gather16_inl_kernel<<<((size_t)N * 8 + B - 1) / B, B, 0, stream>>>(
            t2, rowptr, srcs_sorted, h2, h2, N);

        // ---- K8: linear layer 3 (16->2) ----
        linear_q2_kernel<16, 2, true><<<linGrid, B, 0, stream>>>(
            h2, Wrel3, Wroot3, b3, t3, nullptr, h3, N);
        // ---- K9: gather layer 3 + softmax ----
        gather2_inl_kernel<<<((size_t)N * 4 + B - 1) / B, B, 0, stream>>>(
            t3, rowptr, srcs_sorted, h3, (float*)d_out, N);
    } else {
        // ---- fallback: R2 atomic-scatter path (all f32, ping-pong layout) ----
        float* regionA = (float*)d_ws;
        float* regionB = regionA + (size_t)N * 32;
        float* ft1 = regionA;
        float* fh1 = regionB;
        float* ft2 = regionA;
        float* fh2 = regionA + (size_t)N * 16;
        float* ft3 = regionB;
        float* fh3 = regionB + (size_t)N * 2;
        linear2_kernel<64, 32, false><<<linGrid, B, 0, stream>>>(z, Wrel1, Wroot1, b1, ft1, fh1, N);
        scatter_kernel<32><<<((size_t)nE * 32 + B - 1) / B, B, 0, stream>>>(ft1, src, dst, fh1, nE);
        linear2_kernel<32, 16, true><<<linGrid, B, 0, stream>>>(fh1, Wrel2, Wroot2, b2, ft2, fh2, N);
        scatter_kernel<16><<<((size_t)nE * 16 + B - 1) / B, B, 0, stream>>>(ft2, src, dst, fh2, nE);
        linear2_kernel<16, 2, true><<<linGrid, B, 0, stream>>>(fh2, Wrel3, Wroot3, b3, ft3, fh3, N);
        scatter_kernel<2><<<((size_t)nE * 2 + B - 1) / B, B, 0, stream>>>(ft3, src, dst, fh3, nE);
        softmax2_kernel<<<nodeBlocks, B, 0, stream>>>(fh3, (float*)d_out, N);
    }
}

// Round 7
// 234.712 us; speedup vs baseline: 2.9822x; 1.0894x over previous
//
#include <hip/hip_runtime.h>

// 3-layer GraphConv (PyG) + softmax, 100k nodes, 1.6M edges, f32 in/out.
// R2: f32 global atomics ~306G/s scattered -> pull-gather wins.
// R9: fully deterministic build (zero global atomics). gather32 = 44.5us.
// R10: staged gather unroll: NULL -> not latency-bound.
// R11: fp16 t FAILED accuracy (5.08e-2). R12: int16 row-scaled PASSES.
// R13: int16 gathers (half bytes): NULL -> not bytes-bound.
// R14: scale-in-line (half line-reqs): -5us. 243us = BEST. But the 64B
//      padding pushed t2 to 6.4MB -- out of the 4MB per-XCD L2.
// R15: bucket_gather w/ LDS atomics: DISASTER (LDS-atomic serialization).
// R16: launch-graph compression: REGRESSED +13us (merged kernels inherit
//      worst-case register/LDS; per-block local scans redo work). Launch
//      structure is NOT the cost. Reverted to R14.
// R17: per-GROUP (128-node) scales: scale table 400KB -> 3KB (L1-resident,
//      free) => compact rows: t1 64B (no tscale stream, 1 req/edge),
//      t2 32B -> 3.2MB L2-RESIDENT, t3 4B -> 0.4MB. Noise x1.45 vs R12
//      (group max 4096 samples vs row max), still << 2e-2 budget.

#define RNODES 128
#define NB_MAX 1024
#define CH 4096            // edges per chunk
#define CMAX 512           // max chunks (scan_chunkhist: one chunk/thread)

// ================= device bodies for the linear ============================
template <int Fin, int Fout, bool RELU>
__device__ __forceinline__ void lin_compute(const float* __restrict__ x,
                                            const float* __restrict__ W,
                                            int n, float* o) {
#pragma unroll
    for (int f = 0; f < Fout; ++f) o[f] = 0.f;
    const float* xr = x + (size_t)n * Fin;
#pragma unroll
    for (int k = 0; k < Fin; k += 4) {
        float4 v = *(const float4*)(xr + k);
        if (RELU) {
            v.x = fmaxf(v.x, 0.f); v.y = fmaxf(v.y, 0.f);
            v.z = fmaxf(v.z, 0.f); v.w = fmaxf(v.w, 0.f);
        }
        const float xv[4] = {v.x, v.y, v.z, v.w};
#pragma unroll
        for (int kk = 0; kk < 4; ++kk) {
            const float* wr = W + (size_t)(k + kk) * Fout;
#pragma unroll
            for (int f = 0; f < Fout; ++f)
                o[f] = fmaf(xv[kk], wr[f], o[f]);
        }
    }
}

// ------- split linear: y=0: t=quant(x@Wrel) int16, per-128-node group scale;
//         y=1: acc=x@Wroot+b (f32).  blockDim MUST be 256 (4 waves).
// Fout==32: t stride 32 shorts (64B rows). Fout==16: stride 16 (32B rows).
// Fout==2: stride 2 shorts (4B rows, packed int).
template <int Fin, int Fout, bool RELU>
__global__ void linear_qg_kernel(const float* __restrict__ x,
                                 const float* __restrict__ Wrel,
                                 const float* __restrict__ Wroot,
                                 const float* __restrict__ bias,
                                 short* __restrict__ t,
                                 float* __restrict__ gscale,
                                 float* __restrict__ acc, int N) {
    int n = blockIdx.x * blockDim.x + threadIdx.x;
    const bool valid = (n < N);
    float o[Fout];

    if (blockIdx.y != 0) {
        if (!valid) return;
        lin_compute<Fin, Fout, RELU>(x, Wroot, n, o);
#pragma unroll
        for (int f = 0; f < Fout; ++f) o[f] += bias[f];
        float* arow = acc + (size_t)n * Fout;
        if constexpr (Fout >= 4) {
#pragma unroll
            for (int f = 0; f < Fout; f += 4)
                *(float4*)(arow + f) = make_float4(o[f], o[f+1], o[f+2], o[f+3]);
        } else {
            *(float2*)arow = make_float2(o[0], o[1]);
        }
        return;
    }

    // --- rel path: compute, group-max reduce, quantize compact ---
    float m = 0.f;
    if (valid) {
        lin_compute<Fin, Fout, RELU>(x, Wrel, n, o);
#pragma unroll
        for (int f = 0; f < Fout; ++f) m = fmaxf(m, fabsf(o[f]));
    }
    // wave max (64 lanes)
    float wm = m;
#pragma unroll
    for (int off = 1; off < 64; off <<= 1)
        wm = fmaxf(wm, __shfl_xor(wm, off, 64));
    __shared__ float wmax[4];
    const int wv = threadIdx.x >> 6;            // wave id 0..3
    if ((threadIdx.x & 63) == 0) wmax[wv] = wm;
    __syncthreads();
    // group of 128 nodes = 2 waves: {0,1} and {2,3}
    const float g = fmaxf(wmax[wv & 2], wmax[(wv & 2) | 1]);
    if (!valid) return;
    const float inv = (g > 0.f) ? (32767.0f / g) : 0.f;
    if ((threadIdx.x & 127) == 0) gscale[n >> 7] = g * (1.0f / 32767.0f);

    short q[Fout];
#pragma unroll
    for (int f = 0; f < Fout; ++f) q[f] = (short)__float2int_rn(o[f] * inv);

    if constexpr (Fout == 32) {
        short* trow = t + (size_t)n * 32;           // 64B compact rows
#pragma unroll
        for (int f = 0; f < 32; f += 8)
            *(int4*)(trow + f) = *(const int4*)(q + f);
    } else if constexpr (Fout == 16) {
        short* trow = t + (size_t)n * 16;           // 32B compact rows
        *(int4*)(trow)     = *(const int4*)(q);
        *(int4*)(trow + 8) = *(const int4*)(q + 8);
    } else {
        ((int*)t)[n] = (int)(unsigned short)q[0] | ((int)q[1] << 16);  // 4B rows
    }
}

// ---------------- build step 1: per-chunk LDS histogram --------------------
__global__ void hist_chunked_kernel(const int* __restrict__ dst,
                                    int* __restrict__ chunkhist,
                                    int nE, int NB) {
    __shared__ int h[NB_MAX];
    const int c  = blockIdx.x;
    const int e0 = c * CH, e1 = min(e0 + CH, nE);
    for (int b = threadIdx.x; b < NB; b += blockDim.x) h[b] = 0;
    __syncthreads();
    for (int e = e0 + threadIdx.x; e < e1; e += blockDim.x)
        atomicAdd(&h[dst[e] >> 7], 1);
    __syncthreads();
    for (int b = threadIdx.x; b < NB; b += blockDim.x)
        chunkhist[(size_t)c * NB + b] = h[b];          // contiguous row flush
}

// ---------------- build step 2: column scan (per bucket over chunks) -------
__global__ void scan_chunkhist_kernel(int* __restrict__ chunkhist,
                                      int* __restrict__ gtotal,
                                      int C, int NB) {
    __shared__ int s[CMAX];
    const int b = blockIdx.x;
    const int t = threadIdx.x;
    int v = (t < C) ? chunkhist[(size_t)t * NB + b] : 0;
    s[t] = v;
    __syncthreads();
    for (int off = 1; off < CMAX; off <<= 1) {
        int u = (t >= off) ? s[t - off] : 0;
        __syncthreads();
        s[t] += u;
        __syncthreads();
    }
    if (t < C) chunkhist[(size_t)t * NB + b] = s[t] - v;   // exclusive
    if (t == CMAX - 1) gtotal[b] = s[t];                   // inclusive total
}

// ---------------- build step 3: bucket scan (single block) -----------------
__global__ void scan_buckets_kernel(const int* __restrict__ gtotal,
                                    int* __restrict__ bptr, int NB, int nE) {
    __shared__ int s[NB_MAX];
    int t = threadIdx.x;
    int own = (t < NB) ? gtotal[t] : 0;
    s[t] = own;
    __syncthreads();
    for (int off = 1; off < NB_MAX; off <<= 1) {
        int v = (t >= off) ? s[t - off] : 0;
        __syncthreads();
        s[t] += v;
        __syncthreads();
    }
    if (t < NB) bptr[t] = s[t] - own;
    if (t == 0) bptr[NB] = nE;
}

// ---------------- build step 4: deterministic placement --------------------
__global__ void bucketize_det_kernel(const int* __restrict__ src,
                                     const int* __restrict__ dst,
                                     const int* __restrict__ chunkpre,
                                     const int* __restrict__ bptr,
                                     unsigned int* __restrict__ records,
                                     int nE, int NB) {
    __shared__ int lcur[NB_MAX];
    const int c  = blockIdx.x;
    const int e0 = c * CH, e1 = min(e0 + CH, nE);
    for (int b = threadIdx.x; b < NB; b += blockDim.x)
        lcur[b] = bptr[b] + chunkpre[(size_t)c * NB + b];
    __syncthreads();
    for (int e = e0 + threadIdx.x; e < e1; e += blockDim.x) {
        int d = dst[e];
        int b = d >> 7;
        int pos = atomicAdd(&lcur[b], 1);                  // LDS-only atomic
        records[pos] = (unsigned int)src[e] | ((unsigned int)(d & 127) << 17);
    }
}

// ---------------- build step 5: per-bucket hist+scan+rowptr+place ----------
__global__ void place_merge_kernel(const unsigned int* __restrict__ records,
                                   const int* __restrict__ bptr,
                                   int* __restrict__ rowptr,
                                   int* __restrict__ srcs_sorted,
                                   int N, int nE, int NB) {
    __shared__ int hist[RNODES];
    __shared__ int s[RNODES];
    __shared__ int lcur[RNODES];
    const int b    = blockIdx.x;
    const int base = b * RNODES;
    const int nn   = min(RNODES, N - base);
    const int beg  = bptr[b], end = bptr[b + 1];
    const int t    = threadIdx.x;

    if (t < RNODES) hist[t] = 0;
    __syncthreads();
    for (int i = beg + t; i < end; i += blockDim.x)
        atomicAdd(&hist[records[i] >> 17], 1);
    __syncthreads();

    if (t < RNODES) s[t] = hist[t];
    __syncthreads();
    for (int off = 1; off < RNODES; off <<= 1) {
        int v = (t < RNODES && t >= off) ? s[t - off] : 0;
        __syncthreads();
        if (t < RNODES && t >= off) s[t] += v;
        __syncthreads();
    }
    if (t < nn) {
        int ex = beg + s[t] - hist[t];
        rowptr[base + t] = ex;
        lcur[t] = ex;
    }
    if (b == NB - 1 && t == 0) rowptr[N] = nE;
    __syncthreads();

    for (int i = beg + t; i < end; i += blockDim.x) {
        unsigned int rec = records[i];
        int pos = atomicAdd(&lcur[rec >> 17], 1);
        srcs_sorted[pos] = (int)(rec & 0x1FFFFu);
    }
}

// ------- L1 gather: 64B rows + group scale (L1-resident, 1 req/edge) -------
// 16 lanes/node, each owns one short2 (2 features).
__global__ void gather32_g_kernel(const short* __restrict__ t,
                                  const float* __restrict__ gscale,
                                  const int* __restrict__ rowptr,
                                  const int* __restrict__ srcs,
                                  const float* __restrict__ rootacc,
                                  float* __restrict__ out, int N) {
    int tid = blockIdx.x * blockDim.x + threadIdx.x;
    int n  = tid >> 4;
    int fp = tid & 15;
    if (n >= N) return;

    const int* tp = (const int*)t;              // 16 ints per row (64B)
    int beg = rowptr[n], end = rowptr[n + 1];
    float sx = 0.f, sy = 0.f;
    int e = beg;
    for (; e + 8 <= end; e += 8) {
        int s[8];
#pragma unroll
        for (int u = 0; u < 8; ++u) s[u] = srcs[e + u];
        int q[8]; float sc[8];
#pragma unroll
        for (int u = 0; u < 8; ++u) {
            q[u]  = tp[(size_t)s[u] * 16 + fp];
            sc[u] = gscale[s[u] >> 7];          // 3KB table: L1-hit
        }
#pragma unroll
        for (int u = 0; u < 8; ++u) {
            sx = fmaf(sc[u], (float)((short)(q[u] & 0xFFFF)), sx);
            sy = fmaf(sc[u], (float)(q[u] >> 16), sy);
        }
    }
    for (; e < end; ++e) {
        int s0 = srcs[e];
        int qv = tp[(size_t)s0 * 16 + fp];
        float sc = gscale[s0 >> 7];
        sx = fmaf(sc, (float)((short)(qv & 0xFFFF)), sx);
        sy = fmaf(sc, (float)(qv >> 16), sy);
    }

    const float2 r0 = *(const float2*)(rootacc + (size_t)n * 32 + 2 * fp);
    *(float2*)(out + (size_t)n * 32 + 2 * fp) = make_float2(r0.x + sx, r0.y + sy);
}

// ------- L2 gather: 32B compact rows (3.2MB, L2-resident) + group scale ----
// 8 lanes/node.
__global__ void gather16_g_kernel(const short* __restrict__ t,
                                  const float* __restrict__ gscale,
                                  const int* __restrict__ rowptr,
                                  const int* __restrict__ srcs,
                                  const float* __restrict__ rootacc,
                                  float* __restrict__ out, int N) {
    int tid = blockIdx.x * blockDim.x + threadIdx.x;
    int n  = tid >> 3;
    int fp = tid & 7;
    if (n >= N) return;

    const int* tp = (const int*)t;              // 8 ints per row (32B)
    int beg = rowptr[n], end = rowptr[n + 1];
    float sx = 0.f, sy = 0.f;
    int e = beg;
    for (; e + 8 <= end; e += 8) {
        int s[8];
#pragma unroll
        for (int u = 0; u < 8; ++u) s[u] = srcs[e + u];
        int q[8]; float sc[8];
#pragma unroll
        for (int u = 0; u < 8; ++u) {
            q[u]  = tp[(size_t)s[u] * 8 + fp];
            sc[u] = gscale[s[u] >> 7];
        }
#pragma unroll
        for (int u = 0; u < 8; ++u) {
            sx = fmaf(sc[u], (float)((short)(q[u] & 0xFFFF)), sx);
            sy = fmaf(sc[u], (float)(q[u] >> 16), sy);
        }
    }
    for (; e < end; ++e) {
        int s0 = srcs[e];
        int qv = tp[(size_t)s0 * 8 + fp];
        float sc = gscale[s0 >> 7];
        sx = fmaf(sc, (float)((short)(qv & 0xFFFF)), sx);
        sy = fmaf(sc, (float)(qv >> 16), sy);
    }

    const float2 r0 = *(const float2*)(rootacc + (size_t)n * 16 + 2 * fp);
    *(float2*)(out + (size_t)n * 16 + 2 * fp) = make_float2(r0.x + sx, r0.y + sy);
}

// ------- L3 gather: 4B rows (0.4MB) + group scale, 4 lanes/node ------------
__global__ void gather2_g_kernel(const short* __restrict__ t,
                                 const float* __restrict__ gscale,
                                 const int* __restrict__ rowptr,
                                 const int* __restrict__ srcs,
                                 const float* __restrict__ rootacc,
                                 float* __restrict__ out, int N) {
    int tid = blockIdx.x * blockDim.x + threadIdx.x;
    int n  = tid >> 2;
    int fp = tid & 3;
    if (n >= N) return;

    const int* tp = (const int*)t;              // 4B rows (packed short2)
    int beg = rowptr[n], end = rowptr[n + 1];
    float sx = 0.f, sy = 0.f;
    int e = beg + fp;
    for (; e + 12 < end; e += 16) {
        int s0 = srcs[e], s1 = srcs[e + 4], s2 = srcs[e + 8], s3 = srcs[e + 12];
        int r0 = tp[s0], r1 = tp[s1], r2 = tp[s2], r3 = tp[s3];
        float c0 = gscale[s0 >> 7], c1 = gscale[s1 >> 7];
        float c2 = gscale[s2 >> 7], c3 = gscale[s3 >> 7];
        sx = fmaf(c0, (float)((short)(r0 & 0xFFFF)), sx);
        sy = fmaf(c0, (float)(r0 >> 16), sy);
        sx = fmaf(c1, (float)((short)(r1 & 0xFFFF)), sx);
        sy = fmaf(c1, (float)(r1 >> 16), sy);
        sx = fmaf(c2, (float)((short)(r2 & 0xFFFF)), sx);
        sy = fmaf(c2, (float)(r2 >> 16), sy);
        sx = fmaf(c3, (float)((short)(r3 & 0xFFFF)), sx);
        sy = fmaf(c3, (float)(r3 >> 16), sy);
    }
    for (; e < end; e += 4) {
        int s0 = srcs[e];
        int r = tp[s0];
        float c = gscale[s0 >> 7];
        sx = fmaf(c, (float)((short)(r & 0xFFFF)), sx);
        sy = fmaf(c, (float)(r >> 16), sy);
    }
    sx += __shfl_xor(sx, 1, 64); sy += __shfl_xor(sy, 1, 64);
    sx += __shfl_xor(sx, 2, 64); sy += __shfl_xor(sy, 2, 64);

    if (fp == 0) {
        const float2 r0 = *(const float2*)(rootacc + (size_t)n * 2);
        float a = r0.x + sx, b = r0.y + sy;
        float m = fmaxf(a, b);
        float ea = __expf(a - m), eb = __expf(b - m);
        float inv = 1.0f / (ea + eb);
        *(float2*)(out + (size_t)n * 2) = make_float2(ea * inv, eb * inv);
    }
}

// ---------------- fallback (R2 atomic path) --------------------------------
template <int Fin, int Fout, bool RELU>
__global__ void linear2_kernel(const float* __restrict__ x,
                               const float* __restrict__ Wrel,
                               const float* __restrict__ Wroot,
                               const float* __restrict__ bias,
                               float* __restrict__ t,
                               float* __restrict__ acc, int N) {
    const bool rootTask = (blockIdx.y != 0);
    const float* __restrict__ W = rootTask ? Wroot : Wrel;
    float* __restrict__ outp    = rootTask ? acc : t;

    int n = blockIdx.x * blockDim.x + threadIdx.x;
    if (n >= N) return;

    float o[Fout];
    lin_compute<Fin, Fout, RELU>(x, W, n, o);
    if (rootTask) {
#pragma unroll
        for (int f = 0; f < Fout; ++f) o[f] += bias[f];
    }
    float* op = outp + (size_t)n * Fout;
    if constexpr (Fout >= 4) {
#pragma unroll
        for (int f = 0; f < Fout; f += 4)
            *(float4*)(op + f) = make_float4(o[f], o[f + 1], o[f + 2], o[f + 3]);
    } else {
        *(float2*)op = make_float2(o[0], o[1]);
    }
}

template <int F>
__global__ void scatter_kernel(const float* __restrict__ t,
                               const int* __restrict__ src,
                               const int* __restrict__ dst,
                               float* __restrict__ acc, int nE) {
    int tid = blockIdx.x * blockDim.x + threadIdx.x;
    int e = tid / F;
    if (e >= nE) return;
    int f = tid & (F - 1);
    atomicAdd(acc + (long)dst[e] * F + f, t[(long)src[e] * F + f]);
}

__global__ void softmax2_kernel(const float* __restrict__ h, float* __restrict__ out, int N) {
    int n = blockIdx.x * blockDim.x + threadIdx.x;
    if (n >= N) return;
    float a = h[2 * n], b = h[2 * n + 1];
    float m = fmaxf(a, b);
    float ea = __expf(a - m), eb = __expf(b - m);
    float inv = 1.0f / (ea + eb);
    out[2 * n] = ea * inv;
    out[2 * n + 1] = eb * inv;
}

extern "C" void kernel_launch(void* const* d_in, const int* in_sizes, int n_in,
                              void* d_out, int out_size, void* d_ws, size_t ws_size,
                              hipStream_t stream) {
    const float* z      = (const float*)d_in[0];
    const int*   ei     = (const int*)d_in[1];
    const float* Wrel1  = (const float*)d_in[2];
    const float* Wroot1 = (const float*)d_in[3];
    const float* b1     = (const float*)d_in[4];
    const float* Wrel2  = (const float*)d_in[5];
    const float* Wroot2 = (const float*)d_in[6];
    const float* b2     = (const float*)d_in[7];
    const float* Wrel3  = (const float*)d_in[8];
    const float* Wroot3 = (const float*)d_in[9];
    const float* b3     = (const float*)d_in[10];

    const int N  = in_sizes[0] / 64;   // 100000
    const int nE = in_sizes[1] / 2;    // 1600000
    const int* src = ei;
    const int* dst = ei + nE;
    const int NB = (N + RNODES - 1) / RNODES;   // 782
    const int C  = (nE + CH - 1) / CH;          // 391 chunks

    // ---- flat workspace layout (no aliasing) ----
    char* wsb = (char*)d_ws;
    size_t off = 0;
    auto take = [&](size_t bytes) -> void* {
        void* p = (void*)(wsb + off);
        off = (off + bytes + 255) & ~(size_t)255;
        return p;
    };
    int*          chunkhist   = (int*)take((size_t)CMAX * NB_MAX * 4);
    int*          gtotal      = (int*)take((size_t)NB_MAX * 4);
    int*          bptr        = (int*)take((size_t)(NB_MAX + 1) * 4);
    unsigned int* records     = (unsigned int*)take((size_t)nE * 4);
    int*          rowptr      = (int*)take((size_t)(N + 1) * 4);
    int*          srcs_sorted = (int*)take((size_t)nE * 4);
    short*        t1          = (short*)take((size_t)N * 32 * 2);   // 64B rows
    float*        gs1         = (float*)take((size_t)NB_MAX * 4);   // 3KB
    float*        h1          = (float*)take((size_t)N * 32 * 4);
    short*        t2          = (short*)take((size_t)N * 16 * 2);   // 32B rows, 3.2MB
    float*        gs2         = (float*)take((size_t)NB_MAX * 4);
    float*        h2          = (float*)take((size_t)N * 16 * 4);
    short*        t3          = (short*)take((size_t)N * 2 * 2);    // 4B rows, 0.4MB
    float*        gs3         = (float*)take((size_t)NB_MAX * 4);
    float*        h3          = (float*)take((size_t)N * 2 * 4);
    const size_t needed = off;

    const int B = 256;
    const int nodeBlocks = (N + B - 1) / B;
    const dim3 linGrid(nodeBlocks, 2);       // y=0: rel(quant)->t, y=1: root+b->acc
    const bool packOK = (N <= (1 << 17)) && (NB <= NB_MAX) && (C <= CMAX);

    if (ws_size >= needed && packOK) {
        // ---- build: zero-global-atomic deterministic CSR (R14-proven) ----
        hist_chunked_kernel<<<C, 512, 0, stream>>>(dst, chunkhist, nE, NB);
        scan_chunkhist_kernel<<<NB, CMAX, 0, stream>>>(chunkhist, gtotal, C, NB);
        scan_buckets_kernel<<<1, NB_MAX, 0, stream>>>(gtotal, bptr, NB, nE);
        bucketize_det_kernel<<<C, 512, 0, stream>>>(src, dst, chunkhist, bptr, records, nE, NB);
        place_merge_kernel<<<NB, 512, 0, stream>>>(records, bptr, rowptr, srcs_sorted, N, nE, NB);

        // ---- Layer 1: 64 -> 32 ----
        linear_qg_kernel<64, 32, false><<<linGrid, B, 0, stream>>>(
            z, Wrel1, Wroot1, b1, t1, gs1, h1, N);
        gather32_g_kernel<<<((size_t)N * 16 + B - 1) / B, B, 0, stream>>>(
            t1, gs1, rowptr, srcs_sorted, h1, h1, N);

        // ---- Layer 2: 32 -> 16 ----
        linear_qg_kernel<32, 16, true><<<linGrid, B, 0, stream>>>(
            h1, Wrel2, Wroot2, b2, t2, gs2, h2, N);
        gather16_g_kernel<<<((size_t)N * 8 + B - 1) / B, B, 0, stream>>>(
            t2, gs2, rowptr, srcs_sorted, h2, h2, N);

        // ---- Layer 3: 16 -> 2, softmax fused ----
        linear_qg_kernel<16, 2, true><<<linGrid, B, 0, stream>>>(
            h2, Wrel3, Wroot3, b3, t3, gs3, h3, N);
        gather2_g_kernel<<<((size_t)N * 4 + B - 1) / B, B, 0, stream>>>(
            t3, gs3, rowptr, srcs_sorted, h3, (float*)d_out, N);
    } else {
        // ---- fallback: R2 atomic-scatter path (all f32, ping-pong layout) ----
        float* regionA = (float*)d_ws;
        float* regionB = regionA + (size_t)N * 32;
        float* ft1 = regionA;
        float* fh1 = regionB;
        float* ft2 = regionA;
        float* fh2 = regionA + (size_t)N * 16;
        float* ft3 = regionB;
        float* fh3 = regionB + (size_t)N * 2;
        linear2_kernel<64, 32, false><<<linGrid, B, 0, stream>>>(z, Wrel1, Wroot1, b1, ft1, fh1, N);
        scatter_kernel<32><<<((size_t)nE * 32 + B - 1) / B, B, 0, stream>>>(ft1, src, dst, fh1, nE);
        linear2_kernel<32, 16, true><<<linGrid, B, 0, stream>>>(fh1, Wrel2, Wroot2, b2, ft2, fh2, N);
        scatter_kernel<16><<<((size_t)nE * 16 + B - 1) / B, B, 0, stream>>>(ft2, src, dst, fh2, nE);
        linear2_kernel<16, 2, true><<<linGrid, B, 0, stream>>>(fh2, Wrel3, Wroot3, b3, ft3, fh3, N);
        scatter_kernel<2><<<((size_t)nE * 2 + B - 1) / B, B, 0, stream>>>(ft3, src, dst, fh3, nE);
        softmax2_kernel<<<nodeBlocks, B, 0, stream>>>(fh3, (float*)d_out, N);
    }
}